// Round 1
// baseline (910.968 us; speedup 1.0000x reference)
//
#include <hip/hip_runtime.h>

// Problem constants
#define B_SZ   16
#define P_IN   6400      // 80*80
#define H_IN   80
#define OUTHW  160
#define NCLASS 8
#define C1_IN  256
#define C1_OUT 512
#define C2_OUT 256
#define C3_OUT 128

#define TM 128
#define TN 128
#define TK 16

// Y[b,m,n] = relu( sum_k W[m,k] * X[b,k,n] + bias[m] )
__global__ __launch_bounds__(256, 2)
void gemm_bias_relu(const float* __restrict__ W, const float* __restrict__ bias,
                    const float* __restrict__ X, float* __restrict__ Y,
                    int M, int K, int N)
{
    const int b  = blockIdx.z;
    const int n0 = blockIdx.x * TN;
    const int m0 = blockIdx.y * TM;
    const float* __restrict__ Xb = X + (size_t)b * K * N;
    float* __restrict__ Yb       = Y + (size_t)b * M * N;

    __shared__ float As[TK][TM + 4];   // k-major, padded: scatter-store is 2-way (free)
    __shared__ float Bs[TK][TN];

    const int tid = threadIdx.x;
    const int ty  = tid >> 4;   // 0..15 -> rows
    const int tx  = tid & 15;   // 0..15 -> cols

    float acc[8][8];
#pragma unroll
    for (int i = 0; i < 8; ++i)
#pragma unroll
        for (int j = 0; j < 8; ++j) acc[i][j] = 0.f;

    for (int k0 = 0; k0 < K; k0 += TK) {
        // A tile: 128 rows x 16 k  (W is MxK row-major) -> transpose into As[k][m]
#pragma unroll
        for (int r = 0; r < 2; ++r) {
            int f  = tid + r * 256;          // 0..511 float4 index
            int m  = f >> 2;                 // 0..127
            int kq = (f & 3) << 2;           // 0,4,8,12
            const float4 v = *reinterpret_cast<const float4*>(
                W + (size_t)(m0 + m) * K + k0 + kq);
            As[kq + 0][m] = v.x; As[kq + 1][m] = v.y;
            As[kq + 2][m] = v.z; As[kq + 3][m] = v.w;
        }
        // B tile: 16 k-rows x 128 n (X rows are contiguous in n)
#pragma unroll
        for (int r = 0; r < 2; ++r) {
            int f  = tid + r * 256;
            int kk = f >> 5;                 // 0..15
            int nn = (f & 31) << 2;          // 0..124
            *reinterpret_cast<float4*>(&Bs[kk][nn]) =
                *reinterpret_cast<const float4*>(Xb + (size_t)(k0 + kk) * N + n0 + nn);
        }
        __syncthreads();

#pragma unroll
        for (int kk = 0; kk < TK; ++kk) {
            float a[8], bb[8];
            *reinterpret_cast<float4*>(&a[0]) = *reinterpret_cast<const float4*>(&As[kk][ty * 4]);
            *reinterpret_cast<float4*>(&a[4]) = *reinterpret_cast<const float4*>(&As[kk][64 + ty * 4]);
            *reinterpret_cast<float4*>(&bb[0]) = *reinterpret_cast<const float4*>(&Bs[kk][tx * 4]);
            *reinterpret_cast<float4*>(&bb[4]) = *reinterpret_cast<const float4*>(&Bs[kk][64 + tx * 4]);
#pragma unroll
            for (int i = 0; i < 8; ++i)
#pragma unroll
                for (int j = 0; j < 8; ++j)
                    acc[i][j] = fmaf(a[i], bb[j], acc[i][j]);
        }
        __syncthreads();
    }

    // epilogue: bias + relu, coalesced float4 stores
#pragma unroll
    for (int i = 0; i < 8; ++i) {
        int m = m0 + ((i < 4) ? (ty * 4 + i) : (64 + ty * 4 + (i - 4)));
        const float bi = bias[m];
#pragma unroll
        for (int h = 0; h < 2; ++h) {
            float4 v;
            v.x = fmaxf(acc[i][h * 4 + 0] + bi, 0.f);
            v.y = fmaxf(acc[i][h * 4 + 1] + bi, 0.f);
            v.z = fmaxf(acc[i][h * 4 + 2] + bi, 0.f);
            v.w = fmaxf(acc[i][h * 4 + 3] + bi, 0.f);
            int n = n0 + (h ? (64 + tx * 4) : (tx * 4));
            *reinterpret_cast<float4*>(Yb + (size_t)m * N + n) = v;
        }
    }
}

// Scatter bilinear weights per (batch,class) into g[b][k][p_in], and count labels.
// jax bilinear (antialias=False, 80->160): out i maps to x = 0.5*i - 0.25.
// even i=2m: taps (m-1,0.25),(m,0.75); odd i=2m+1: taps (m,0.75),(m+1,0.25).
// Edge renormalization == clamp index and keep both taps (weights sum to 1).
__global__ void label_scatter(const int* __restrict__ lbl,
                              float* __restrict__ g, float* __restrict__ counts)
{
    __shared__ float hist[NCLASS];
    const int b   = blockIdx.x;
    const int tid = threadIdx.x;
    const int pix = blockIdx.y * 256 + tid;   // 0..25599
    if (tid < NCLASS) hist[tid] = 0.f;
    __syncthreads();

    const int i = pix / OUTHW;
    const int j = pix - i * OUTHW;
    const int k = lbl[(size_t)b * (OUTHW * OUTHW) + pix];

    const int mi = i >> 1, mj = j >> 1;
    int y0, y1, x0, x1; float wy0, wy1, wx0, wx1;
    if (i & 1) { y0 = mi; y1 = (mi < H_IN - 1) ? mi + 1 : H_IN - 1; wy0 = 0.75f; wy1 = 0.25f; }
    else       { y0 = (mi > 0) ? mi - 1 : 0; y1 = mi;               wy0 = 0.25f; wy1 = 0.75f; }
    if (j & 1) { x0 = mj; x1 = (mj < H_IN - 1) ? mj + 1 : H_IN - 1; wx0 = 0.75f; wx1 = 0.25f; }
    else       { x0 = (mj > 0) ? mj - 1 : 0; x1 = mj;               wx0 = 0.25f; wx1 = 0.75f; }

    float* gb = g + ((size_t)(b * NCLASS + k)) * P_IN;
    atomicAdd(&gb[y0 * H_IN + x0], wy0 * wx0);
    atomicAdd(&gb[y0 * H_IN + x1], wy0 * wx1);
    atomicAdd(&gb[y1 * H_IN + x0], wy1 * wx0);
    atomicAdd(&gb[y1 * H_IN + x1], wy1 * wx1);

    atomicAdd(&hist[k], 1.f);
    __syncthreads();
    if (tid < NCLASS) atomicAdd(&counts[b * NCLASS + tid], hist[tid]);
}

// pooled[b,k,c] = (sum_p f2[b,c,p] * g[b,k,p]) / (counts[b,k]+eps); plus presence.
// One wave per (b,c): coalesced p-strided loads; g is 3.3MB -> L2 resident.
__global__ __launch_bounds__(256)
void pool_write(const float* __restrict__ f2, const float* __restrict__ g,
                const float* __restrict__ counts, float* __restrict__ out)
{
    const int b    = blockIdx.x;          // 16
    const int wave = threadIdx.x >> 6;    // 0..3
    const int lane = threadIdx.x & 63;
    const int c    = blockIdx.y * 4 + wave;   // grid.y = 32 -> c in 0..127

    const float* fb = f2 + ((size_t)b * C3_OUT + c) * P_IN;
    const float* gb = g + (size_t)b * NCLASS * P_IN;

    float acc[NCLASS];
#pragma unroll
    for (int k = 0; k < NCLASS; ++k) acc[k] = 0.f;

    for (int p = lane; p < P_IN; p += 64) {
        const float fv = fb[p];
#pragma unroll
        for (int k = 0; k < NCLASS; ++k)
            acc[k] = fmaf(fv, gb[(size_t)k * P_IN + p], acc[k]);
    }
#pragma unroll
    for (int k = 0; k < NCLASS; ++k) {
        float v = acc[k];
        for (int off = 32; off; off >>= 1) v += __shfl_down(v, off);
        if (lane == 0) {
            const float cnt = counts[b * NCLASS + k];
            out[((size_t)b * NCLASS + k) * C3_OUT + c] = v / (cnt + 1e-8f);
        }
    }
    // presence (b,k) -> written once per batch by blocks with blockIdx.y==0
    if (blockIdx.y == 0 && threadIdx.x < NCLASS) {
        out[B_SZ * NCLASS * C3_OUT + b * NCLASS + threadIdx.x] =
            (counts[b * NCLASS + threadIdx.x] > 0.f) ? 1.0f : 0.0f;
    }
}

extern "C" void kernel_launch(void* const* d_in, const int* in_sizes, int n_in,
                              void* d_out, int out_size, void* d_ws, size_t ws_size,
                              hipStream_t stream)
{
    const float* feature = (const float*)d_in[0];
    const int*   lbl     = (const int*)d_in[1];
    const float* w1 = (const float*)d_in[2];
    const float* b1 = (const float*)d_in[3];
    const float* w2 = (const float*)d_in[4];
    const float* b2 = (const float*)d_in[5];
    const float* w3 = (const float*)d_in[6];
    const float* b3 = (const float*)d_in[7];
    float* out = (float*)d_out;

    char* ws = (char*)d_ws;
    // f1: 16*512*6400 f32 = 209,715,200 B at offset 0
    // f : 16*256*6400 f32 = 104,857,600 B at offset 209,715,200
    // f2: 16*128*6400 f32 =  52,428,800 B at offset 0 (reuses dead f1)
    // g : 16*8*6400  f32  =   3,276,800 B at offset 314,572,800
    // counts: 128 f32     =         512 B after g
    float* f1     = (float*)(ws);
    float* f      = (float*)(ws + 209715200);
    float* f2     = (float*)(ws);
    float* g      = (float*)(ws + 314572800);
    float* counts = (float*)(ws + 314572800 + 3276800);

    hipMemsetAsync(g, 0, 3276800 + 512, stream);

    dim3 blk(256);
    gemm_bias_relu<<<dim3(P_IN / TN, C1_OUT / TM, B_SZ), blk, 0, stream>>>(
        w1, b1, feature, f1, C1_OUT, C1_IN, P_IN);
    gemm_bias_relu<<<dim3(P_IN / TN, C2_OUT / TM, B_SZ), blk, 0, stream>>>(
        w2, b2, f1, f, C2_OUT, C1_OUT, P_IN);
    gemm_bias_relu<<<dim3(P_IN / TN, C3_OUT / TM, B_SZ), blk, 0, stream>>>(
        w3, b3, f, f2, C3_OUT, C2_OUT, P_IN);
    label_scatter<<<dim3(B_SZ, (OUTHW * OUTHW) / 256), blk, 0, stream>>>(lbl, g, counts);
    pool_write<<<dim3(B_SZ, C3_OUT / 4), blk, 0, stream>>>(f2, g, counts, out);
}

// Round 2
// 565.811 us; speedup vs baseline: 1.6100x; 1.6100x over previous
//
#include <hip/hip_runtime.h>

#define B_SZ   16
#define P_IN   6400
#define H_IN   80
#define OUTHW  160
#define NCLASS 8

typedef __attribute__((ext_vector_type(8))) short  short8v;
typedef __attribute__((ext_vector_type(4))) float  f32x4;
typedef __attribute__((ext_vector_type(4))) unsigned short ushort4v;

__device__ __forceinline__ unsigned short f2bf(float x) {
    union { float f; unsigned int u; } v; v.f = x;
    unsigned int r = v.u + 0x7fffu + ((v.u >> 16) & 1u);   // RNE
    return (unsigned short)(r >> 16);
}
__device__ __forceinline__ float bf2f(unsigned short h) {
    union { unsigned int u; float f; } v; v.u = ((unsigned int)h) << 16;
    return v.f;
}

__device__ __forceinline__ void gload16(const unsigned short* g, unsigned short* lds) {
    __builtin_amdgcn_global_load_lds(
        (const __attribute__((address_space(1))) unsigned int*)g,
        (__attribute__((address_space(3))) unsigned int*)lds, 16, 0, 0);
}

// ---------- prep: fp32 -> bf16 hi/lo ----------
__global__ void wprep(const float* __restrict__ w, unsigned short* __restrict__ wh,
                      unsigned short* __restrict__ wl, int n) {
    int i = blockIdx.x * 256 + threadIdx.x;
    if (i < n) {
        float v = w[i];
        unsigned short h = f2bf(v);
        wh[i] = h;
        wl[i] = f2bf(v - bf2f(h));
    }
}

// feature [b][c=256][p=6400] fp32 -> Xh/Xl [b][p][c] bf16
__global__ void fprep(const float* __restrict__ feat,
                      unsigned short* __restrict__ xh, unsigned short* __restrict__ xl) {
    __shared__ float t[32][257];
    const int b = blockIdx.y, p0 = blockIdx.x * 32;
    const int pi = threadIdx.x & 31, cg = threadIdx.x >> 5;   // cg 0..7
    const float* fb = feat + (size_t)b * 256 * P_IN;
#pragma unroll 4
    for (int cc = 0; cc < 32; ++cc) {
        int c = cc * 8 + cg;
        t[pi][c] = fb[(size_t)c * P_IN + p0 + pi];
    }
    __syncthreads();
#pragma unroll 4
    for (int r = 0; r < 32; ++r) {
        float v = t[r][threadIdx.x];
        unsigned short h = f2bf(v);
        size_t o = ((size_t)b * P_IN + p0 + r) * 256 + threadIdx.x;
        xh[o] = h;
        xl[o] = f2bf(v - bf2f(h));
    }
}

// ---------- MFMA conv: Y[b][n][m] = relu( sum_k W[m][k]*X[b][n][k] + bias[m] ) ----------
// 128x128 tile, BK=64, 4 waves (2x2), wave tile 64x64 (4x4 fragments 16x16x32).
// Split precision: X=Xh+Xl, W=Wh+Wl; acc += AhBh + AhBl + AlBh.
// LDS: 16B-chunk XOR swizzle (kc ^ row&7), linear dest + pre-swizzled global source.
template<int K, bool FP32OUT>
__global__ __launch_bounds__(256, 2)
void conv_mfma(const unsigned short* __restrict__ Wh, const unsigned short* __restrict__ Wl,
               const float* __restrict__ bias,
               const unsigned short* __restrict__ Xh, const unsigned short* __restrict__ Xl,
               unsigned short* __restrict__ Yh, unsigned short* __restrict__ Yl,
               float* __restrict__ Yf, int M)
{
    __shared__ unsigned short As_h[8192], As_l[8192], Bs_h[8192], Bs_l[8192];
    const int tid = threadIdx.x, lane = tid & 63, w = tid >> 6;
    const int wm = w >> 1, wn = w & 1;
    const int b = blockIdx.z, n0 = blockIdx.x * 128, m0 = blockIdx.y * 128;
    const size_t xbase = ((size_t)b * P_IN + n0) * K;

    f32x4 acc[4][4];
#pragma unroll
    for (int i = 0; i < 4; ++i)
#pragma unroll
        for (int j = 0; j < 4; ++j) acc[i][j] = (f32x4)0.f;

    const int srow = lane >> 3;      // 0..7
    const int scol = lane & 7;

    for (int k0 = 0; k0 < K; k0 += 64) {
#pragma unroll
        for (int q = 0; q < 4; ++q) {
            const int c   = w * 4 + q;            // chunk 0..15 (16 rows each... 8 rows/chunk)
            const int row = c * 8 + srow;         // tile row 0..127
            const int kc  = scol ^ (row & 7);     // inverse-swizzled source chunk
            const size_t ga = (size_t)(m0 + row) * K + k0 + kc * 8;
            const size_t gx = xbase + (size_t)row * K + k0 + kc * 8;
            const int lo = c * 512;               // ushort offset of 1KB chunk
            gload16(Wh + ga, &As_h[lo]);
            gload16(Wl + ga, &As_l[lo]);
            gload16(Xh + gx, &Bs_h[lo]);
            gload16(Xl + gx, &Bs_l[lo]);
        }
        __syncthreads();
#pragma unroll
        for (int s = 0; s < 2; ++s) {
            short8v ah[4], al[4], bh[4], bl[4];
            const int kc = s * 4 + (lane >> 4);
#pragma unroll
            for (int mi = 0; mi < 4; ++mi) {
                const int m = wm * 64 + mi * 16 + (lane & 15);
                const int off = m * 64 + ((kc ^ (m & 7)) << 3);
                ah[mi] = *(const short8v*)&As_h[off];
                al[mi] = *(const short8v*)&As_l[off];
            }
#pragma unroll
            for (int ni = 0; ni < 4; ++ni) {
                const int n = wn * 64 + ni * 16 + (lane & 15);
                const int off = n * 64 + ((kc ^ (n & 7)) << 3);
                bh[ni] = *(const short8v*)&Bs_h[off];
                bl[ni] = *(const short8v*)&Bs_l[off];
            }
#pragma unroll
            for (int mi = 0; mi < 4; ++mi)
#pragma unroll
                for (int ni = 0; ni < 4; ++ni) {
                    acc[mi][ni] = __builtin_amdgcn_mfma_f32_16x16x32_bf16(ah[mi], bh[ni], acc[mi][ni], 0, 0, 0);
                    acc[mi][ni] = __builtin_amdgcn_mfma_f32_16x16x32_bf16(ah[mi], bl[ni], acc[mi][ni], 0, 0, 0);
                    acc[mi][ni] = __builtin_amdgcn_mfma_f32_16x16x32_bf16(al[mi], bh[ni], acc[mi][ni], 0, 0, 0);
                }
        }
        __syncthreads();
    }

    // epilogue: D col = n (lane&15), row = m ((lane>>4)*4 + j) -> 4 consecutive m per lane
    const int lhi = lane >> 4;
#pragma unroll
    for (int mi = 0; mi < 4; ++mi) {
        const int m_base = m0 + wm * 64 + mi * 16 + lhi * 4;
        const float4 b4 = *(const float4*)&bias[m_base];
#pragma unroll
        for (int ni = 0; ni < 4; ++ni) {
            const int n = n0 + wn * 64 + ni * 16 + (lane & 15);
            const size_t o = ((size_t)b * P_IN + n) * M + m_base;
            const float v0 = fmaxf(acc[mi][ni][0] + b4.x, 0.f);
            const float v1 = fmaxf(acc[mi][ni][1] + b4.y, 0.f);
            const float v2 = fmaxf(acc[mi][ni][2] + b4.z, 0.f);
            const float v3 = fmaxf(acc[mi][ni][3] + b4.w, 0.f);
            if constexpr (FP32OUT) {
                float4 r; r.x = v0; r.y = v1; r.z = v2; r.w = v3;
                *(float4*)&Yf[o] = r;
            } else {
                ushort4v h, l;
                h.x = f2bf(v0); l.x = f2bf(v0 - bf2f(h.x));
                h.y = f2bf(v1); l.y = f2bf(v1 - bf2f(h.y));
                h.z = f2bf(v2); l.z = f2bf(v2 - bf2f(h.z));
                h.w = f2bf(v3); l.w = f2bf(v3 - bf2f(h.w));
                *(ushort4v*)&Yh[o] = h;
                *(ushort4v*)&Yl[o] = l;
            }
        }
    }
}

// ---------- label scatter (unchanged, verified exact in R1) ----------
__global__ void label_scatter(const int* __restrict__ lbl,
                              float* __restrict__ g, float* __restrict__ counts)
{
    __shared__ float hist[NCLASS];
    const int b   = blockIdx.x;
    const int tid = threadIdx.x;
    const int pix = blockIdx.y * 256 + tid;
    if (tid < NCLASS) hist[tid] = 0.f;
    __syncthreads();

    const int i = pix / OUTHW;
    const int j = pix - i * OUTHW;
    const int k = lbl[(size_t)b * (OUTHW * OUTHW) + pix];

    const int mi = i >> 1, mj = j >> 1;
    int y0, y1, x0, x1; float wy0, wy1, wx0, wx1;
    if (i & 1) { y0 = mi; y1 = (mi < H_IN - 1) ? mi + 1 : H_IN - 1; wy0 = 0.75f; wy1 = 0.25f; }
    else       { y0 = (mi > 0) ? mi - 1 : 0; y1 = mi;               wy0 = 0.25f; wy1 = 0.75f; }
    if (j & 1) { x0 = mj; x1 = (mj < H_IN - 1) ? mj + 1 : H_IN - 1; wx0 = 0.75f; wx1 = 0.25f; }
    else       { x0 = (mj > 0) ? mj - 1 : 0; x1 = mj;               wx0 = 0.25f; wx1 = 0.75f; }

    float* gb = g + ((size_t)(b * NCLASS + k)) * P_IN;
    atomicAdd(&gb[y0 * H_IN + x0], wy0 * wx0);
    atomicAdd(&gb[y0 * H_IN + x1], wy0 * wx1);
    atomicAdd(&gb[y1 * H_IN + x0], wy1 * wx0);
    atomicAdd(&gb[y1 * H_IN + x1], wy1 * wx1);

    atomicAdd(&hist[k], 1.f);
    __syncthreads();
    if (tid < NCLASS) atomicAdd(&counts[b * NCLASS + tid], hist[tid]);
}

// ---------- pool: pooled[b][k][c] += sum_p g[b][k][p] * f3[b][p][c] ----------
__global__ __launch_bounds__(256)
void pool2(const float* __restrict__ f3, const float* __restrict__ g,
           float* __restrict__ pooled)
{
    __shared__ float sg[NCLASS][800];
    const int b = blockIdx.x, chunk = blockIdx.y;   // chunk of 800 p
    const int tid = threadIdx.x;
#pragma unroll
    for (int i = 0; i < 25; ++i) {
        int idx = i * 256 + tid;
        int k = idx / 800, p = idx - k * 800;
        sg[k][p] = g[((size_t)b * NCLASS + k) * P_IN + chunk * 800 + p];
    }
    __syncthreads();

    const int c  = tid & 127;
    const int kg = tid >> 7;   // 0..1 -> classes kg*4..+3
    float acc0 = 0.f, acc1 = 0.f, acc2 = 0.f, acc3 = 0.f;
    const float* fb = f3 + ((size_t)b * P_IN + chunk * 800) * 128 + c;
    for (int p = 0; p < 800; ++p) {
        const float fv = fb[(size_t)p * 128];
        acc0 = fmaf(fv, sg[kg * 4 + 0][p], acc0);
        acc1 = fmaf(fv, sg[kg * 4 + 1][p], acc1);
        acc2 = fmaf(fv, sg[kg * 4 + 2][p], acc2);
        acc3 = fmaf(fv, sg[kg * 4 + 3][p], acc3);
    }
    atomicAdd(&pooled[((size_t)b * NCLASS + kg * 4 + 0) * 128 + c], acc0);
    atomicAdd(&pooled[((size_t)b * NCLASS + kg * 4 + 1) * 128 + c], acc1);
    atomicAdd(&pooled[((size_t)b * NCLASS + kg * 4 + 2) * 128 + c], acc2);
    atomicAdd(&pooled[((size_t)b * NCLASS + kg * 4 + 3) * 128 + c], acc3);
}

__global__ void finalize(const float* __restrict__ pooled, const float* __restrict__ counts,
                         float* __restrict__ out)
{
    const int b = blockIdx.x;
#pragma unroll
    for (int i = threadIdx.x; i < NCLASS * 128; i += 256) {
        const int k = i >> 7;
        const float cnt = counts[b * NCLASS + k];
        out[(size_t)b * NCLASS * 128 + i] = pooled[(size_t)b * NCLASS * 128 + i] / (cnt + 1e-8f);
    }
    if (threadIdx.x < NCLASS)
        out[B_SZ * NCLASS * 128 + b * NCLASS + threadIdx.x] =
            (counts[b * NCLASS + threadIdx.x] > 0.f) ? 1.f : 0.f;
}

extern "C" void kernel_launch(void* const* d_in, const int* in_sizes, int n_in,
                              void* d_out, int out_size, void* d_ws, size_t ws_size,
                              hipStream_t stream)
{
    const float* feature = (const float*)d_in[0];
    const int*   lbl     = (const int*)d_in[1];
    const float* w1 = (const float*)d_in[2];
    const float* b1 = (const float*)d_in[3];
    const float* w2 = (const float*)d_in[4];
    const float* b2 = (const float*)d_in[5];
    const float* w3 = (const float*)d_in[6];
    const float* b3 = (const float*)d_in[7];
    float* out = (float*)d_out;

    char* ws = (char*)d_ws;
    // [0, 104857600): Xh+Xl (conv1 in), later f2h+f2l (conv2 out / conv3 in)
    // [104857600, 314572800): f1h+f1l (conv1 out / conv2 in); f3 fp32 overlays first 52.4MB after conv2
    unsigned short* Xh  = (unsigned short*)(ws);
    unsigned short* Xl  = (unsigned short*)(ws + 52428800);
    unsigned short* f1h = (unsigned short*)(ws + 104857600);
    unsigned short* f1l = (unsigned short*)(ws + 209715200);
    unsigned short* f2h = (unsigned short*)(ws);             // overlays Xh (dead)
    unsigned short* f2l = (unsigned short*)(ws + 52428800);  // overlays Xl (dead)
    float*          f3  = (float*)(ws + 104857600);          // overlays f1h (dead)
    unsigned short* Wh1 = (unsigned short*)(ws + 314572800);
    unsigned short* Wl1 = (unsigned short*)(ws + 314834944);
    unsigned short* Wh2 = (unsigned short*)(ws + 315097088);
    unsigned short* Wl2 = (unsigned short*)(ws + 315359232);
    unsigned short* Wh3 = (unsigned short*)(ws + 315621376);
    unsigned short* Wl3 = (unsigned short*)(ws + 315686912);
    float* g      = (float*)(ws + 315752448);
    float* counts = (float*)(ws + 319029248);
    float* pooled = (float*)(ws + 319029760);
    // end: 319095296 bytes

    hipMemsetAsync(g, 0, 3276800 + 512 + 65536, stream);

    wprep<<<512, 256, 0, stream>>>(w1, Wh1, Wl1, 512 * 256);
    wprep<<<512, 256, 0, stream>>>(w2, Wh2, Wl2, 256 * 512);
    wprep<<<128, 256, 0, stream>>>(w3, Wh3, Wl3, 128 * 256);
    fprep<<<dim3(200, 16), 256, 0, stream>>>(feature, Xh, Xl);

    conv_mfma<256, false><<<dim3(50, 4, 16), 256, 0, stream>>>(
        Wh1, Wl1, b1, Xh, Xl, f1h, f1l, nullptr, 512);
    conv_mfma<512, false><<<dim3(50, 2, 16), 256, 0, stream>>>(
        Wh2, Wl2, b2, f1h, f1l, f2h, f2l, nullptr, 256);
    conv_mfma<256, true><<<dim3(50, 1, 16), 256, 0, stream>>>(
        Wh3, Wl3, b3, f2h, f2l, nullptr, nullptr, f3, 128);

    label_scatter<<<dim3(B_SZ, (OUTHW * OUTHW) / 256), 256, 0, stream>>>(lbl, g, counts);
    pool2<<<dim3(B_SZ, 8), 256, 0, stream>>>(f3, g, pooled);
    finalize<<<B_SZ, 256, 0, stream>>>(pooled, counts, out);
}

// Round 3
// 406.813 us; speedup vs baseline: 2.2393x; 1.3908x over previous
//
#include <hip/hip_runtime.h>

#define B_SZ   16
#define P_IN   6400
#define H_IN   80
#define OUTHW  160
#define NCLASS 8

typedef __attribute__((ext_vector_type(8))) short  short8v;
typedef __attribute__((ext_vector_type(4))) float  f32x4;
typedef __attribute__((ext_vector_type(4))) unsigned short ushort4v;
typedef __attribute__((ext_vector_type(2))) unsigned short ushort2v;

__device__ __forceinline__ unsigned short f2bf(float x) {
    union { float f; unsigned int u; } v; v.f = x;
    unsigned int r = v.u + 0x7fffu + ((v.u >> 16) & 1u);   // RNE
    return (unsigned short)(r >> 16);
}
__device__ __forceinline__ float bf2f(unsigned short h) {
    union { unsigned int u; float f; } v; v.u = ((unsigned int)h) << 16;
    return v.f;
}

__device__ __forceinline__ void gload16(const unsigned short* g, unsigned short* lds) {
    __builtin_amdgcn_global_load_lds(
        (const __attribute__((address_space(1))) unsigned int*)g,
        (__attribute__((address_space(3))) unsigned int*)lds, 16, 0, 0);
}

// ---------- prep: weights fp32 -> bf16 hi/lo (correlated error must stay compensated) ----------
__global__ void wprep(const float* __restrict__ w, unsigned short* __restrict__ wh,
                      unsigned short* __restrict__ wl, int n) {
    int i = blockIdx.x * 256 + threadIdx.x;
    if (i < n) {
        float v = w[i];
        unsigned short h = f2bf(v);
        wh[i] = h;
        wl[i] = f2bf(v - bf2f(h));
    }
}

// feature [b][c=256][p=6400] fp32 -> Xh [b][p][c] bf16 (single stream)
__global__ void fprep(const float* __restrict__ feat, unsigned short* __restrict__ xh) {
    __shared__ float t[32][257];
    const int b = blockIdx.y, p0 = blockIdx.x * 32;
    const int pi = threadIdx.x & 31, cg = threadIdx.x >> 5;   // cg 0..7
    const float* fb = feat + (size_t)b * 256 * P_IN;
#pragma unroll 4
    for (int cc = 0; cc < 32; ++cc) {
        int c = cc * 8 + cg;
        t[pi][c] = fb[(size_t)c * P_IN + p0 + pi];
    }
    __syncthreads();
    const int rr  = threadIdx.x >> 7;      // 0..1 row offset
    const int cc2 = threadIdx.x & 127;     // c-pair
#pragma unroll 4
    for (int r = 0; r < 32; r += 2) {
        const int row = r + rr;
        ushort2v u;
        u.x = f2bf(t[row][cc2 * 2]);
        u.y = f2bf(t[row][cc2 * 2 + 1]);
        *(ushort2v*)&xh[((size_t)b * P_IN + p0 + row) * 256 + cc2 * 2] = u;
    }
}

// ---------- MFMA conv: Y[b][n][m] = relu( sum_k W[m][k]*X[b][n][k] + bias[m] ) ----------
// 128x128 tile, BK=64, 4 waves (2x2), wave tile 64x64, fragments 16x16x32.
// W split hi/lo (2 MFMA), X plain bf16. 16B-chunk XOR swizzle, pre-swizzled
// global source + swizzled read (G21). XCD-chunked 1-D grid, m fastest (T1).
template<int K, int NM>
__global__ __launch_bounds__(256, 3)
void conv_mfma(const unsigned short* __restrict__ Wh, const unsigned short* __restrict__ Wl,
               const float* __restrict__ bias,
               const unsigned short* __restrict__ X, unsigned short* __restrict__ Y)
{
    constexpr int M = NM * 128;
    __shared__ unsigned short As_h[8192], As_l[8192], Bs[8192];
    const int tid = threadIdx.x, lane = tid & 63, w = tid >> 6;
    const int wm = w >> 1, wn = w & 1;

    // bijective XCD swizzle (nblocks % 8 == 0 for all three convs)
    const int nb = gridDim.x;
    const int id = blockIdx.x;
    const int wg = (id & 7) * (nb >> 3) + (id >> 3);
    const int b   = wg / (50 * NM);
    const int rem = wg - b * (50 * NM);
    const int n0 = (rem / NM) * 128;
    const int m0 = (rem - (rem / NM) * NM) * 128;

    const size_t xbase = ((size_t)b * P_IN + n0) * K;

    f32x4 acc[4][4];
#pragma unroll
    for (int i = 0; i < 4; ++i)
#pragma unroll
        for (int j = 0; j < 4; ++j) acc[i][j] = (f32x4)0.f;

    const int srow = lane >> 3;      // 0..7
    const int scol = lane & 7;

    for (int k0 = 0; k0 < K; k0 += 64) {
#pragma unroll
        for (int q = 0; q < 4; ++q) {
            const int c   = w * 4 + q;            // 1KB chunk 0..15 (8 rows each)
            const int row = c * 8 + srow;
            const int kc  = scol ^ (row & 7);     // inverse-swizzled source chunk
            const size_t ga = (size_t)(m0 + row) * K + k0 + kc * 8;
            const size_t gx = xbase + (size_t)row * K + k0 + kc * 8;
            const int lo = c * 512;
            gload16(Wh + ga, &As_h[lo]);
            gload16(Wl + ga, &As_l[lo]);
            gload16(X + gx, &Bs[lo]);
        }
        __syncthreads();
#pragma unroll
        for (int s = 0; s < 2; ++s) {
            short8v ah[4], al[4], bb[4];
            const int kc = s * 4 + (lane >> 4);
#pragma unroll
            for (int mi = 0; mi < 4; ++mi) {
                const int m = wm * 64 + mi * 16 + (lane & 15);
                const int off = m * 64 + ((kc ^ (m & 7)) << 3);
                ah[mi] = *(const short8v*)&As_h[off];
                al[mi] = *(const short8v*)&As_l[off];
            }
#pragma unroll
            for (int ni = 0; ni < 4; ++ni) {
                const int n = wn * 64 + ni * 16 + (lane & 15);
                const int off = n * 64 + ((kc ^ (n & 7)) << 3);
                bb[ni] = *(const short8v*)&Bs[off];
            }
#pragma unroll
            for (int mi = 0; mi < 4; ++mi)
#pragma unroll
                for (int ni = 0; ni < 4; ++ni) {
                    acc[mi][ni] = __builtin_amdgcn_mfma_f32_16x16x32_bf16(ah[mi], bb[ni], acc[mi][ni], 0, 0, 0);
                    acc[mi][ni] = __builtin_amdgcn_mfma_f32_16x16x32_bf16(al[mi], bb[ni], acc[mi][ni], 0, 0, 0);
                }
        }
        __syncthreads();
    }

    // epilogue: D col=n (lane&15), row=m ((lane>>4)*4+j) -> 4 consecutive m per lane
    const int lhi = lane >> 4;
#pragma unroll
    for (int mi = 0; mi < 4; ++mi) {
        const int m_base = m0 + wm * 64 + mi * 16 + lhi * 4;
        const float4 b4 = *(const float4*)&bias[m_base];
#pragma unroll
        for (int ni = 0; ni < 4; ++ni) {
            const int n = n0 + wn * 64 + ni * 16 + (lane & 15);
            const size_t o = ((size_t)b * P_IN + n) * M + m_base;
            ushort4v u;
            u.x = f2bf(fmaxf(acc[mi][ni][0] + b4.x, 0.f));
            u.y = f2bf(fmaxf(acc[mi][ni][1] + b4.y, 0.f));
            u.z = f2bf(fmaxf(acc[mi][ni][2] + b4.z, 0.f));
            u.w = f2bf(fmaxf(acc[mi][ni][3] + b4.w, 0.f));
            *(ushort4v*)&Y[o] = u;
        }
    }
}

// ---------- label scatter (verified exact in R1) ----------
__global__ void label_scatter(const int* __restrict__ lbl,
                              float* __restrict__ g, float* __restrict__ counts)
{
    __shared__ float hist[NCLASS];
    const int b   = blockIdx.x;
    const int tid = threadIdx.x;
    const int pix = blockIdx.y * 256 + tid;
    if (tid < NCLASS) hist[tid] = 0.f;
    __syncthreads();

    const int i = pix / OUTHW;
    const int j = pix - i * OUTHW;
    const int k = lbl[(size_t)b * (OUTHW * OUTHW) + pix];

    const int mi = i >> 1, mj = j >> 1;
    int y0, y1, x0, x1; float wy0, wy1, wx0, wx1;
    if (i & 1) { y0 = mi; y1 = (mi < H_IN - 1) ? mi + 1 : H_IN - 1; wy0 = 0.75f; wy1 = 0.25f; }
    else       { y0 = (mi > 0) ? mi - 1 : 0; y1 = mi;               wy0 = 0.25f; wy1 = 0.75f; }
    if (j & 1) { x0 = mj; x1 = (mj < H_IN - 1) ? mj + 1 : H_IN - 1; wx0 = 0.75f; wx1 = 0.25f; }
    else       { x0 = (mj > 0) ? mj - 1 : 0; x1 = mj;               wx0 = 0.25f; wx1 = 0.75f; }

    float* gb = g + ((size_t)(b * NCLASS + k)) * P_IN;
    atomicAdd(&gb[y0 * H_IN + x0], wy0 * wx0);
    atomicAdd(&gb[y0 * H_IN + x1], wy0 * wx1);
    atomicAdd(&gb[y1 * H_IN + x0], wy1 * wx0);
    atomicAdd(&gb[y1 * H_IN + x1], wy1 * wx1);

    atomicAdd(&hist[k], 1.f);
    __syncthreads();
    if (tid < NCLASS) atomicAdd(&counts[b * NCLASS + tid], hist[tid]);
}

// ---------- pool: pooled[b][k][c] += sum_p g[b][k][p] * f3[b][p][c], f3 bf16 ----------
__global__ __launch_bounds__(256)
void pool2(const unsigned short* __restrict__ f3, const float* __restrict__ g,
           float* __restrict__ pooled)
{
    __shared__ float sg[NCLASS][800];
    const int b = blockIdx.x, chunk = blockIdx.y;   // chunk of 800 p
    const int tid = threadIdx.x;
#pragma unroll
    for (int i = 0; i < 25; ++i) {
        int idx = i * 256 + tid;
        int k = idx / 800, p = idx - k * 800;
        sg[k][p] = g[((size_t)b * NCLASS + k) * P_IN + chunk * 800 + p];
    }
    __syncthreads();

    const int c  = tid & 127;
    const int kg = tid >> 7;   // 0..1 -> classes kg*4..+3
    float acc0 = 0.f, acc1 = 0.f, acc2 = 0.f, acc3 = 0.f;
    const unsigned short* fb = f3 + ((size_t)b * P_IN + chunk * 800) * 128 + c;
    for (int p = 0; p < 800; ++p) {
        const float fv = bf2f(fb[(size_t)p * 128]);
        acc0 = fmaf(fv, sg[kg * 4 + 0][p], acc0);
        acc1 = fmaf(fv, sg[kg * 4 + 1][p], acc1);
        acc2 = fmaf(fv, sg[kg * 4 + 2][p], acc2);
        acc3 = fmaf(fv, sg[kg * 4 + 3][p], acc3);
    }
    atomicAdd(&pooled[((size_t)b * NCLASS + kg * 4 + 0) * 128 + c], acc0);
    atomicAdd(&pooled[((size_t)b * NCLASS + kg * 4 + 1) * 128 + c], acc1);
    atomicAdd(&pooled[((size_t)b * NCLASS + kg * 4 + 2) * 128 + c], acc2);
    atomicAdd(&pooled[((size_t)b * NCLASS + kg * 4 + 3) * 128 + c], acc3);
}

__global__ void finalize(const float* __restrict__ pooled, const float* __restrict__ counts,
                         float* __restrict__ out)
{
    const int b = blockIdx.x;
#pragma unroll
    for (int i = threadIdx.x; i < NCLASS * 128; i += 256) {
        const int k = i >> 7;
        const float cnt = counts[b * NCLASS + k];
        out[(size_t)b * NCLASS * 128 + i] = pooled[(size_t)b * NCLASS * 128 + i] / (cnt + 1e-8f);
    }
    if (threadIdx.x < NCLASS)
        out[B_SZ * NCLASS * 128 + b * NCLASS + threadIdx.x] =
            (counts[b * NCLASS + threadIdx.x] > 0.f) ? 1.f : 0.f;
}

extern "C" void kernel_launch(void* const* d_in, const int* in_sizes, int n_in,
                              void* d_out, int out_size, void* d_ws, size_t ws_size,
                              hipStream_t stream)
{
    const float* feature = (const float*)d_in[0];
    const int*   lbl     = (const int*)d_in[1];
    const float* w1 = (const float*)d_in[2];
    const float* b1 = (const float*)d_in[3];
    const float* w2 = (const float*)d_in[4];
    const float* b2 = (const float*)d_in[5];
    const float* w3 = (const float*)d_in[6];
    const float* b3 = (const float*)d_in[7];
    float* out = (float*)d_out;

    char* ws = (char*)d_ws;
    unsigned short* Xh  = (unsigned short*)(ws);               // 52,428,800
    unsigned short* f1  = (unsigned short*)(ws + 52428800);    // 104,857,600
    unsigned short* f2  = (unsigned short*)(ws + 157286400);   // 52,428,800
    unsigned short* f3  = (unsigned short*)(ws + 209715200);   // 26,214,400
    unsigned short* Wh1 = (unsigned short*)(ws + 235929600);
    unsigned short* Wl1 = (unsigned short*)(ws + 236191744);
    unsigned short* Wh2 = (unsigned short*)(ws + 236453888);
    unsigned short* Wl2 = (unsigned short*)(ws + 236716032);
    unsigned short* Wh3 = (unsigned short*)(ws + 236978176);
    unsigned short* Wl3 = (unsigned short*)(ws + 237043712);
    float* g      = (float*)(ws + 237109248);                  // 3,276,800
    float* counts = (float*)(ws + 240386048);                  // 512
    float* pooled = (float*)(ws + 240386560);                  // 65,536

    hipMemsetAsync(g, 0, 3276800 + 512 + 65536, stream);

    wprep<<<512, 256, 0, stream>>>(w1, Wh1, Wl1, 512 * 256);
    wprep<<<512, 256, 0, stream>>>(w2, Wh2, Wl2, 256 * 512);
    wprep<<<128, 256, 0, stream>>>(w3, Wh3, Wl3, 128 * 256);
    fprep<<<dim3(200, 16), 256, 0, stream>>>(feature, Xh);

    conv_mfma<256, 4><<<3200, 256, 0, stream>>>(Wh1, Wl1, b1, Xh, f1);
    conv_mfma<512, 2><<<1600, 256, 0, stream>>>(Wh2, Wl2, b2, f1, f2);
    conv_mfma<256, 1><<<800,  256, 0, stream>>>(Wh3, Wl3, b3, f2, f3);

    label_scatter<<<dim3(B_SZ, (OUTHW * OUTHW) / 256), 256, 0, stream>>>(lbl, g, counts);
    pool2<<<dim3(B_SZ, 8), 256, 0, stream>>>(f3, g, pooled);
    finalize<<<B_SZ, 256, 0, stream>>>(pooled, counts, out);
}

// Round 4
// 396.570 us; speedup vs baseline: 2.2971x; 1.0258x over previous
//
#include <hip/hip_runtime.h>

#define B_SZ   16
#define P_IN   6400
#define H_IN   80
#define OUTHW  160
#define NCLASS 8

typedef __attribute__((ext_vector_type(8))) short  short8v;
typedef __attribute__((ext_vector_type(4))) float  f32x4;
typedef __attribute__((ext_vector_type(4))) unsigned short ushort4v;
typedef __attribute__((ext_vector_type(2))) unsigned short ushort2v;

__device__ __forceinline__ unsigned short f2bf(float x) {
    union { float f; unsigned int u; } v; v.f = x;
    unsigned int r = v.u + 0x7fffu + ((v.u >> 16) & 1u);   // RNE
    return (unsigned short)(r >> 16);
}
__device__ __forceinline__ float bf2f(unsigned short h) {
    union { unsigned int u; float f; } v; v.u = ((unsigned int)h) << 16;
    return v.f;
}

__device__ __forceinline__ void gload16(const unsigned short* g, unsigned short* lds) {
    __builtin_amdgcn_global_load_lds(
        (const __attribute__((address_space(1))) unsigned int*)g,
        (__attribute__((address_space(3))) unsigned int*)lds, 16, 0, 0);
}

// ---------- fused weight prep: fp32 -> bf16 hi/lo for all three weights ----------
__global__ void wprep3(const float* __restrict__ w1, const float* __restrict__ w2,
                       const float* __restrict__ w3,
                       unsigned short* __restrict__ h1, unsigned short* __restrict__ l1,
                       unsigned short* __restrict__ h2, unsigned short* __restrict__ l2,
                       unsigned short* __restrict__ h3, unsigned short* __restrict__ l3)
{
    int i = blockIdx.x * 256 + threadIdx.x;
    const float* src; unsigned short *h, *l; int off;
    if (i < 131072)      { src = w1; h = h1; l = l1; off = i; }
    else if (i < 262144) { src = w2; h = h2; l = l2; off = i - 131072; }
    else                 { src = w3; h = h3; l = l3; off = i - 262144;
                           if (off >= 32768) return; }
    float v = src[off];
    unsigned short hi = f2bf(v);
    h[off] = hi;
    l[off] = f2bf(v - bf2f(hi));
}

// feature [b][c=256][p=6400] fp32 -> X [b][p][c] bf16
__global__ void fprep(const float* __restrict__ feat, unsigned short* __restrict__ xh) {
    __shared__ float t[32][257];
    const int b = blockIdx.y, p0 = blockIdx.x * 32;
    const int pi = threadIdx.x & 31, cg = threadIdx.x >> 5;   // cg 0..7
    const float* fb = feat + (size_t)b * 256 * P_IN;
#pragma unroll 4
    for (int cc = 0; cc < 32; ++cc) {
        int c = cc * 8 + cg;
        t[pi][c] = fb[(size_t)c * P_IN + p0 + pi];
    }
    __syncthreads();
    const int rr  = threadIdx.x >> 7;      // 0..1 row offset
    const int cc2 = threadIdx.x & 127;     // c-pair
#pragma unroll 4
    for (int r = 0; r < 32; r += 2) {
        const int row = r + rr;
        ushort2v u;
        u.x = f2bf(t[row][cc2 * 2]);
        u.y = f2bf(t[row][cc2 * 2 + 1]);
        *(ushort2v*)&xh[((size_t)b * P_IN + p0 + row) * 256 + cc2 * 2] = u;
    }
}

// ---------- MFMA conv: Y[b][n][m] = relu( sum_k W[m][k]*X[b][n][k] + bias[m] ) ----------
// 128x128 tile, BK=32, double-buffered LDS (T3-minimum 2-phase: STAGE(t+1) issued
// before compute(t), ONE barrier per K-iter). W split hi/lo (2 MFMA), X plain bf16.
// Additive slot swizzle: LDS row r slot s holds global k-group (s-(r>>1))&3 ->
// 16-row fragment column reads spread over all 8 bank groups (2-way, free).
// XCD-chunked 1-D grid, m fastest (T1, bijective since nblocks%8==0).
template<int K, int NM>
__global__ __launch_bounds__(256, 3)
void conv_mfma(const unsigned short* __restrict__ Wh, const unsigned short* __restrict__ Wl,
               const float* __restrict__ bias,
               const unsigned short* __restrict__ X, unsigned short* __restrict__ Y)
{
    constexpr int M  = NM * 128;
    constexpr int NK = K / 32;
    __shared__ unsigned short As_h[2][4096], As_l[2][4096], Bs[2][4096];
    const int tid = threadIdx.x, lane = tid & 63, w = tid >> 6;
    const int wm = w >> 1, wn = w & 1;

    const int nb = gridDim.x;
    const int id = blockIdx.x;
    const int wg = (id & 7) * (nb >> 3) + (id >> 3);
    const int bb  = wg / (50 * NM);
    const int rem = wg - bb * (50 * NM);
    const int n0 = (rem / NM) * 128;
    const int m0 = (rem - (rem / NM) * NM) * 128;

    const size_t abase = (size_t)m0 * K;
    const size_t xbase = ((size_t)bb * P_IN + n0) * K;

    f32x4 acc[4][4];
#pragma unroll
    for (int i = 0; i < 4; ++i)
#pragma unroll
        for (int j = 0; j < 4; ++j) acc[i][j] = (f32x4)0.f;

    // staging geometry: 8 chunks of 1KB per stream; wave w owns chunks {2w, 2w+1}.
    // gload_lds dest is forced linear (base + lane*16B): lane -> row=ch*16+(lane>>2),
    // slot=lane&3. Source k-group for (row,slot): kc = (slot - (row>>1)) & 3.
    int s_row[2], s_k8[2], s_lo[2];
#pragma unroll
    for (int q = 0; q < 2; ++q) {
        const int ch = 2 * w + q;
        s_row[q] = ch * 16 + (lane >> 2);
        s_k8[q]  = ((((lane & 3) - (s_row[q] >> 1)) & 3) << 3);
        s_lo[q]  = ch * 512;
    }
    // fragment read offsets (ushort): row r, want k-group g=lane>>4 -> slot=(g+(r>>1))&3
    int off_a[4], off_b[4];
    const int gsel = lane >> 4;
#pragma unroll
    for (int mi = 0; mi < 4; ++mi) {
        const int r = wm * 64 + mi * 16 + (lane & 15);
        off_a[mi] = r * 32 + (((gsel + (r >> 1)) & 3) << 3);
    }
#pragma unroll
    for (int ni = 0; ni < 4; ++ni) {
        const int r = wn * 64 + ni * 16 + (lane & 15);
        off_b[ni] = r * 32 + (((gsel + (r >> 1)) & 3) << 3);
    }

#define STAGE(buf, kt) do {                                                   \
    _Pragma("unroll")                                                         \
    for (int q = 0; q < 2; ++q) {                                             \
        const size_t kof = (size_t)(kt) * 32 + s_k8[q];                       \
        const size_t gW  = abase + (size_t)s_row[q] * K + kof;                \
        const size_t gX  = xbase + (size_t)s_row[q] * K + kof;                \
        gload16(Wh + gW, &As_h[buf][s_lo[q]]);                                \
        gload16(Wl + gW, &As_l[buf][s_lo[q]]);                                \
        gload16(X  + gX, &Bs[buf][s_lo[q]]);                                  \
    }                                                                         \
} while (0)

    int cur = 0;
    STAGE(0, 0);
    __syncthreads();

    for (int t = 0; t < NK; ++t) {
        if (t + 1 < NK) STAGE(cur ^ 1, t + 1);
        short8v ah[4], al[4], bv[4];
#pragma unroll
        for (int mi = 0; mi < 4; ++mi) {
            ah[mi] = *(const short8v*)&As_h[cur][off_a[mi]];
            al[mi] = *(const short8v*)&As_l[cur][off_a[mi]];
        }
#pragma unroll
        for (int ni = 0; ni < 4; ++ni)
            bv[ni] = *(const short8v*)&Bs[cur][off_b[ni]];
#pragma unroll
        for (int mi = 0; mi < 4; ++mi)
#pragma unroll
            for (int ni = 0; ni < 4; ++ni) {
                acc[mi][ni] = __builtin_amdgcn_mfma_f32_16x16x32_bf16(ah[mi], bv[ni], acc[mi][ni], 0, 0, 0);
                acc[mi][ni] = __builtin_amdgcn_mfma_f32_16x16x32_bf16(al[mi], bv[ni], acc[mi][ni], 0, 0, 0);
            }
        __syncthreads();   // drains vmcnt(0): STAGE(t+1) landed; safe to flip
        cur ^= 1;
    }
#undef STAGE

    // epilogue: D col=n (lane&15), row=m ((lane>>4)*4+j) -> 4 consecutive m per lane
    const int lhi = lane >> 4;
#pragma unroll
    for (int mi = 0; mi < 4; ++mi) {
        const int m_base = m0 + wm * 64 + mi * 16 + lhi * 4;
        const float4 b4 = *(const float4*)&bias[m_base];
#pragma unroll
        for (int ni = 0; ni < 4; ++ni) {
            const int n = n0 + wn * 64 + ni * 16 + (lane & 15);
            const size_t o = ((size_t)bb * P_IN + n) * M + m_base;
            ushort4v u;
            u.x = f2bf(fmaxf(acc[mi][ni][0] + b4.x, 0.f));
            u.y = f2bf(fmaxf(acc[mi][ni][1] + b4.y, 0.f));
            u.z = f2bf(fmaxf(acc[mi][ni][2] + b4.z, 0.f));
            u.w = f2bf(fmaxf(acc[mi][ni][3] + b4.w, 0.f));
            *(ushort4v*)&Y[o] = u;
        }
    }
}

// ---------- label scatter: slab-owned LDS accumulation, no global atomics on g ----------
// Block (b, slab) exclusively owns in-rows [8*slab, 8*slab+8). It processes out-rows
// i in [16*slab-1, 16*slab+17) and accumulates only taps landing in its rows; every
// tap is processed exactly once globally. Counts: out-row i counted by the block
// owning i>>1. Flush = plain coalesced stores covering all of g (no memset needed).
__global__ __launch_bounds__(256)
void label_scatter(const int* __restrict__ lbl, float* __restrict__ g,
                   float* __restrict__ counts)
{
    __shared__ float sg[NCLASS][8][80];   // 20.5 KB
    __shared__ float hist[NCLASS];
    const int b = blockIdx.x, slab = blockIdx.y;
    const int tid = threadIdx.x;
    const int r0 = slab * 8;
    for (int i = tid; i < NCLASS * 8 * 80; i += 256) ((float*)sg)[i] = 0.f;
    if (tid < NCLASS) hist[tid] = 0.f;
    __syncthreads();

    const int ibase = 2 * r0 - 1;
    for (int idx = tid; idx < 18 * 160; idx += 256) {
        const int ir = idx / 160, j = idx - ir * 160;
        const int i = ibase + ir;
        if (i < 0 || i >= OUTHW) continue;
        const int k = lbl[(size_t)b * (OUTHW * OUTHW) + i * OUTHW + j];
        const int mi = i >> 1, mj = j >> 1;
        int y0, y1, x0, x1; float wy0, wy1, wx0, wx1;
        if (i & 1) { y0 = mi; y1 = (mi < H_IN - 1) ? mi + 1 : H_IN - 1; wy0 = 0.75f; wy1 = 0.25f; }
        else       { y0 = (mi > 0) ? mi - 1 : 0; y1 = mi;               wy0 = 0.25f; wy1 = 0.75f; }
        if (j & 1) { x0 = mj; x1 = (mj < H_IN - 1) ? mj + 1 : H_IN - 1; wx0 = 0.75f; wx1 = 0.25f; }
        else       { x0 = (mj > 0) ? mj - 1 : 0; x1 = mj;               wx0 = 0.25f; wx1 = 0.75f; }
        if (mi >= r0 && mi < r0 + 8) atomicAdd(&hist[k], 1.f);
        const int ry0 = y0 - r0, ry1 = y1 - r0;
        if (ry0 >= 0 && ry0 < 8) {
            atomicAdd(&sg[k][ry0][x0], wy0 * wx0);
            atomicAdd(&sg[k][ry0][x1], wy0 * wx1);
        }
        if (ry1 >= 0 && ry1 < 8) {
            atomicAdd(&sg[k][ry1][x0], wy1 * wx0);
            atomicAdd(&sg[k][ry1][x1], wy1 * wx1);
        }
    }
    __syncthreads();
    for (int i = tid; i < NCLASS * 8 * 80; i += 256) {
        const int k = i / 640, rem2 = i - k * 640;
        g[((size_t)b * NCLASS + k) * P_IN + r0 * 80 + rem2] = ((const float*)sg)[i];
    }
    if (tid < NCLASS) atomicAdd(&counts[b * NCLASS + tid], hist[tid]);
}

// ---------- pool: pooled[b][k][c] += sum_p g[b][k][p] * f3[b][p][c], f3 bf16 ----------
__global__ __launch_bounds__(256)
void pool2(const unsigned short* __restrict__ f3, const float* __restrict__ g,
           float* __restrict__ pooled)
{
    __shared__ float sg[NCLASS][800];
    const int b = blockIdx.x, chunk = blockIdx.y;
    const int tid = threadIdx.x;
#pragma unroll
    for (int i = 0; i < 25; ++i) {
        int idx = i * 256 + tid;
        int k = idx / 800, p = idx - k * 800;
        sg[k][p] = g[((size_t)b * NCLASS + k) * P_IN + chunk * 800 + p];
    }
    __syncthreads();

    const int c  = tid & 127;
    const int kg = tid >> 7;
    float acc0 = 0.f, acc1 = 0.f, acc2 = 0.f, acc3 = 0.f;
    const unsigned short* fb = f3 + ((size_t)b * P_IN + chunk * 800) * 128 + c;
    for (int p = 0; p < 800; ++p) {
        const float fv = bf2f(fb[(size_t)p * 128]);
        acc0 = fmaf(fv, sg[kg * 4 + 0][p], acc0);
        acc1 = fmaf(fv, sg[kg * 4 + 1][p], acc1);
        acc2 = fmaf(fv, sg[kg * 4 + 2][p], acc2);
        acc3 = fmaf(fv, sg[kg * 4 + 3][p], acc3);
    }
    atomicAdd(&pooled[((size_t)b * NCLASS + kg * 4 + 0) * 128 + c], acc0);
    atomicAdd(&pooled[((size_t)b * NCLASS + kg * 4 + 1) * 128 + c], acc1);
    atomicAdd(&pooled[((size_t)b * NCLASS + kg * 4 + 2) * 128 + c], acc2);
    atomicAdd(&pooled[((size_t)b * NCLASS + kg * 4 + 3) * 128 + c], acc3);
}

__global__ void finalize(const float* __restrict__ pooled, const float* __restrict__ counts,
                         float* __restrict__ out)
{
    const int b = blockIdx.x;
#pragma unroll
    for (int i = threadIdx.x; i < NCLASS * 128; i += 256) {
        const int k = i >> 7;
        const float cnt = counts[b * NCLASS + k];
        out[(size_t)b * NCLASS * 128 + i] = pooled[(size_t)b * NCLASS * 128 + i] / (cnt + 1e-8f);
    }
    if (threadIdx.x < NCLASS)
        out[B_SZ * NCLASS * 128 + b * NCLASS + threadIdx.x] =
            (counts[b * NCLASS + threadIdx.x] > 0.f) ? 1.f : 0.f;
}

extern "C" void kernel_launch(void* const* d_in, const int* in_sizes, int n_in,
                              void* d_out, int out_size, void* d_ws, size_t ws_size,
                              hipStream_t stream)
{
    const float* feature = (const float*)d_in[0];
    const int*   lbl     = (const int*)d_in[1];
    const float* w1 = (const float*)d_in[2];
    const float* b1 = (const float*)d_in[3];
    const float* w2 = (const float*)d_in[4];
    const float* b2 = (const float*)d_in[5];
    const float* w3 = (const float*)d_in[6];
    const float* b3 = (const float*)d_in[7];
    float* out = (float*)d_out;

    char* ws = (char*)d_ws;
    unsigned short* Xh  = (unsigned short*)(ws);               // 52,428,800
    unsigned short* f1  = (unsigned short*)(ws + 52428800);    // 104,857,600
    unsigned short* f2  = (unsigned short*)(ws + 157286400);   // 52,428,800
    unsigned short* f3  = (unsigned short*)(ws + 209715200);   // 26,214,400
    unsigned short* Wh1 = (unsigned short*)(ws + 235929600);
    unsigned short* Wl1 = (unsigned short*)(ws + 236191744);
    unsigned short* Wh2 = (unsigned short*)(ws + 236453888);
    unsigned short* Wl2 = (unsigned short*)(ws + 236716032);
    unsigned short* Wh3 = (unsigned short*)(ws + 236978176);
    unsigned short* Wl3 = (unsigned short*)(ws + 237043712);
    float* g      = (float*)(ws + 237109248);                  // 3,276,800 (fully written by scatter)
    float* counts = (float*)(ws + 240386048);                  // 512
    float* pooled = (float*)(ws + 240386560);                  // 65,536

    hipMemsetAsync(counts, 0, 512 + 65536, stream);

    wprep3<<<1152, 256, 0, stream>>>(w1, w2, w3, Wh1, Wl1, Wh2, Wl2, Wh3, Wl3);
    fprep<<<dim3(200, 16), 256, 0, stream>>>(feature, Xh);

    conv_mfma<256, 4><<<3200, 256, 0, stream>>>(Wh1, Wl1, b1, Xh, f1);
    conv_mfma<512, 2><<<1600, 256, 0, stream>>>(Wh2, Wl2, b2, f1, f2);
    conv_mfma<256, 1><<<800,  256, 0, stream>>>(Wh3, Wl3, b3, f2, f3);

    label_scatter<<<dim3(B_SZ, 10), 256, 0, stream>>>(lbl, g, counts);
    pool2<<<dim3(B_SZ, 8), 256, 0, stream>>>(f3, g, pooled);
    finalize<<<B_SZ, 256, 0, stream>>>(pooled, counts, out);
}